// Round 1
// 606.419 us; speedup vs baseline: 1.0726x; 1.0726x over previous
//
#include <hip/hip_runtime.h>
#include <stdint.h>

typedef _Float16 f16x8 __attribute__((ext_vector_type(8)));
typedef _Float16 f16x4 __attribute__((ext_vector_type(4)));
typedef float    f32x4 __attribute__((ext_vector_type(4)));

#define NFIELD 64
#define DIM    128
#define BTOT   8192
#define NB     8   // batches per s_kernel block

__device__ __forceinline__ f16x8 cvt8(float4 a, float4 b) {
  f16x8 h;
  h[0] = (_Float16)a.x; h[1] = (_Float16)a.y; h[2] = (_Float16)a.z; h[3] = (_Float16)a.w;
  h[4] = (_Float16)b.x; h[5] = (_Float16)b.y; h[6] = (_Float16)b.z; h[7] = (_Float16)b.w;
  return h;
}

// ---------------- prep: fp16 conversions + W transpose into workspace ----------------
// Wt[i][d][j] = W[i][j][d] (fp16), Kh = fp16(K_w), Qh = fp16(Q_w)
__global__ void prep_kernel(const float* __restrict__ W,
                            const float* __restrict__ Kw,
                            const float* __restrict__ Qw,
                            _Float16* __restrict__ Wt,
                            _Float16* __restrict__ Kh,
                            _Float16* __restrict__ Qh) {
  const int blk = blockIdx.x, t = threadIdx.x;
  if (blk < NFIELD) {
    const float* Wi = W + (size_t)blk * NFIELD * DIM;
    _Float16* Wo = Wt + (size_t)blk * DIM * NFIELD;
    for (int idx = t; idx < DIM * NFIELD; idx += 256) {
      int d = idx >> 6, j = idx & 63;
      Wo[idx] = (_Float16)Wi[j * DIM + d];
    }
  } else if (blk == NFIELD) {
    for (int idx = t; idx < DIM * DIM; idx += 256) Kh[idx] = (_Float16)Kw[idx];
  } else {
    for (int idx = t; idx < DIM * DIM; idx += 256) Qh[idx] = (_Float16)Qw[idx];
  }
}

// ---------------- kernel A: S[b] = F_b @ (F_b @ Kw^T)^T, stored fp16 ----------------
// NB batches per block, 4 waves, software-pipelined:
//   - Kh fragments live in registers for the whole block (loaded once)
//   - F for batch b+2 prefetched into registers while computing batch b
//   - S copied out via LDS with coalesced f16x8 stores
// All LDS tiles XOR-swizzled: byte ^= (row&7)<<4  (<=2-way bank aliasing, free).
__global__ __launch_bounds__(256, 2)
void s_kernel(const float* __restrict__ F,
              const _Float16* __restrict__ Kh,
              _Float16* __restrict__ Sg, int c0) {
  __shared__ __attribute__((aligned(16))) _Float16 sF[2][64 * 128];  // rows of 256B, swizzled
  __shared__ __attribute__((aligned(16))) _Float16 sKf[64 * 128];    // rows of 256B, swizzled
  __shared__ __attribute__((aligned(16))) _Float16 sS[2][64 * 64];   // rows of 128B, swizzled
  const int t = threadIdx.x;
  const int lane = t & 63, wave = t >> 6;
  const int l15 = lane & 15, quad = lane >> 4;
  const int bbase = blockIdx.x * NB;

  // Kh fragments for this wave's two e-tiles (e in [32w, 32w+32)), loaded once per block
  f16x8 kh[2][4];
#pragma unroll
  for (int eh = 0; eh < 2; ++eh)
#pragma unroll
    for (int kt = 0; kt < 4; ++kt)
      kh[eh][kt] = *(const f16x8*)(Kh + ((wave * 2 + eh) * 16 + l15) * DIM + kt * 32 + quad * 8);

  float4 fr[8];
  // prologue: stage batch 0 into sF[0]
  {
    const float4* Fb4 = (const float4*)(F + (size_t)(c0 + bbase) * (NFIELD * DIM));
#pragma unroll
    for (int k = 0; k < 4; ++k) {
      int u = t + k * 256;
      fr[2 * k]     = Fb4[2 * u];
      fr[2 * k + 1] = Fb4[2 * u + 1];
    }
#pragma unroll
    for (int k = 0; k < 4; ++k) {
      int u = t + k * 256;
      int row = u >> 4, c8 = u & 15;
      *(f16x8*)((char*)&sF[0][0] + row * 256 + ((c8 * 16) ^ ((row & 7) << 4))) =
          cvt8(fr[2 * k], fr[2 * k + 1]);
    }
  }
  // issue loads for batch 1 (land during batch-0 compute)
  {
    const float4* Fb4 = (const float4*)(F + (size_t)(c0 + bbase + 1) * (NFIELD * DIM));
#pragma unroll
    for (int k = 0; k < 4; ++k) {
      int u = t + k * 256;
      fr[2 * k]     = Fb4[2 * u];
      fr[2 * k + 1] = Fb4[2 * u + 1];
    }
  }
  __syncthreads();

  for (int bi = 0; bi < NB; ++bi) {
    const int cur = bi & 1;
    const _Float16* sFc = &sF[cur][0];

    // ---- Kf[j,e] = sum_d F[j,d] * Kw[e,d]; wave owns e-tiles {2w,2w+1}
    f16x8 afc[4][4];  // F A-fragments, rows x*16+l15 — reused by the S phase
#pragma unroll
    for (int jt = 0; jt < 4; ++jt)
#pragma unroll
      for (int kt = 0; kt < 4; ++kt) {
        int row = jt * 16 + l15;
        afc[jt][kt] = *(const f16x8*)((const char*)sFc + row * 256 +
                                      ((kt * 64 + quad * 16) ^ ((row & 7) << 4)));
      }
    f32x4 aKf[4][2];
#pragma unroll
    for (int jt = 0; jt < 4; ++jt) {
      aKf[jt][0] = (f32x4){0.f, 0.f, 0.f, 0.f};
      aKf[jt][1] = (f32x4){0.f, 0.f, 0.f, 0.f};
    }
#pragma unroll
    for (int jt = 0; jt < 4; ++jt)
#pragma unroll
      for (int kt = 0; kt < 4; ++kt) {
        aKf[jt][0] = __builtin_amdgcn_mfma_f32_16x16x32_f16(afc[jt][kt], kh[0][kt], aKf[jt][0], 0, 0, 0);
        aKf[jt][1] = __builtin_amdgcn_mfma_f32_16x16x32_f16(afc[jt][kt], kh[1][kt], aKf[jt][1], 0, 0, 0);
      }
    // write Kf (fp16) to sKf; C layout: row j = jt*16+quad*4+r, col e = (2w+eh)*16+l15
#pragma unroll
    for (int jt = 0; jt < 4; ++jt)
#pragma unroll
      for (int eh = 0; eh < 2; ++eh) {
        int e = (wave * 2 + eh) * 16 + l15;
#pragma unroll
        for (int r = 0; r < 4; ++r) {
          int j = jt * 16 + quad * 4 + r;
          *(_Float16*)((char*)sKf + j * 256 + ((e * 2) ^ ((j & 7) << 4))) =
              (_Float16)aKf[jt][eh][r];
        }
      }
    // stage batch bi+1 into sF[cur^1] (regs loaded one iteration ago)
    if (bi + 1 < NB) {
#pragma unroll
      for (int k = 0; k < 4; ++k) {
        int u = t + k * 256;
        int row = u >> 4, c8 = u & 15;
        *(f16x8*)((char*)&sF[cur ^ 1][0] + row * 256 + ((c8 * 16) ^ ((row & 7) << 4))) =
            cvt8(fr[2 * k], fr[2 * k + 1]);
      }
    }
    __syncthreads();  // sKf ready; sF[cur^1] staged

    // issue loads for batch bi+2 (regs now free)
    if (bi + 2 < NB) {
      const float4* Fb4 = (const float4*)(F + (size_t)(c0 + bbase + bi + 2) * (NFIELD * DIM));
#pragma unroll
      for (int k = 0; k < 4; ++k) {
        int u = t + k * 256;
        fr[2 * k]     = Fb4[2 * u];
        fr[2 * k + 1] = Fb4[2 * u + 1];
      }
    }

    // copy out S for batch bi-1 (coalesced f16x8 stores; drains during S compute)
    if (bi > 0) {
      _Float16* dst = Sg + (size_t)(bbase + bi - 1) * (NFIELD * NFIELD);
#pragma unroll
      for (int k = 0; k < 2; ++k) {
        int idx = t + k * 256;
        int si = idx >> 3, j8 = idx & 7;
        f16x8 v = *(const f16x8*)((const char*)&sS[cur ^ 1][0] + si * 128 +
                                  ((j8 * 16) ^ ((si & 7) << 4)));
        *(f16x8*)(dst + si * 64 + j8 * 8) = v;
      }
    }

    // ---- S[i,j] = sum_e F[i,e] * Kf[j,e]; wave owns j-tile = wave
    f16x8 bS[4];
#pragma unroll
    for (int kt = 0; kt < 4; ++kt) {
      int row = wave * 16 + l15;
      bS[kt] = *(const f16x8*)((const char*)sKf + row * 256 +
                               ((kt * 64 + quad * 16) ^ ((row & 7) << 4)));
    }
    f32x4 aS[4];
#pragma unroll
    for (int it = 0; it < 4; ++it) aS[it] = (f32x4){0.f, 0.f, 0.f, 0.f};
#pragma unroll
    for (int it = 0; it < 4; ++it)
#pragma unroll
      for (int kt = 0; kt < 4; ++kt)
        aS[it] = __builtin_amdgcn_mfma_f32_16x16x32_f16(afc[it][kt], bS[kt], aS[it], 0, 0, 0);
#pragma unroll
    for (int it = 0; it < 4; ++it)
#pragma unroll
      for (int r = 0; r < 4; ++r) {
        int si = it * 16 + quad * 4 + r, j = wave * 16 + l15;
        *(_Float16*)((char*)&sS[cur][0] + si * 128 + ((j * 2) ^ ((si & 7) << 4))) =
            (_Float16)aS[it][r];
      }
    __syncthreads();  // sS[cur] ready; sF[cur] & sKf free for next iteration
  }
  // epilogue: copy out S for batch NB-1
  {
    const int cur = (NB - 1) & 1;
    _Float16* dst = Sg + (size_t)(bbase + NB - 1) * (NFIELD * NFIELD);
#pragma unroll
    for (int k = 0; k < 2; ++k) {
      int idx = t + k * 256;
      int si = idx >> 3, j8 = idx & 7;
      f16x8 v = *(const f16x8*)((const char*)&sS[cur][0] + si * 128 +
                                ((j8 * 16) ^ ((si & 7) << 4)));
      *(f16x8*)(dst + si * 64 + j8 * 8) = v;
    }
  }
}

// ---------------- kernel B: out[b,i,:] = S[b,i,:]@W[i] + F[b,i,:]@Qw^T ----------------
// grid (b-chunks of 128, i in 0..63). Augmented GEMM: [128 x 192] @ [192 x 128].
// All A fragments preloaded into registers before the barrier -> MFMA loop has no
// global latency on its critical path.
__global__ __launch_bounds__(256, 2)
void out_kernel(const float* __restrict__ F,
                const _Float16* __restrict__ Sg,
                const _Float16* __restrict__ Wt,
                const _Float16* __restrict__ Qh,
                float* __restrict__ Out, int c0) {
  __shared__ __attribute__((aligned(16))) _Float16 sBt[128 * 200];  // row stride 400B
  const int i = blockIdx.y;
  const int t = threadIdx.x;
  const int lane = t & 63, wave = t >> 6;
  const int l15 = lane & 15, quad = lane >> 4;

  // stage B^T rows: [Wt[i][d][0:64] | Qh[d][0:128]]
  const f16x8* wp = (const f16x8*)(Wt + (size_t)i * DIM * NFIELD);
#pragma unroll
  for (int k = 0; k < 4; ++k) {
    int idx = t + k * 256;
    int d = idx >> 3, jw = idx & 7;
    *(f16x8*)&sBt[d * 200 + jw * 8] = wp[idx];
  }
  const f16x8* qp = (const f16x8*)Qh;
#pragma unroll
  for (int k = 0; k < 8; ++k) {
    int idx = t + k * 256;
    int d = idx >> 4, ew = idx & 15;
    *(f16x8*)&sBt[d * 200 + 64 + ew * 8] = qp[idx];
  }

  // preload ALL A fragments: S (fp16) + F (raw fp32, converted at use)
  const int bl0 = blockIdx.x * 128;
  f16x8 aS[2][2];
  float4 fr[2][8];
#pragma unroll
  for (int mi = 0; mi < 2; ++mi) {
    const int bl = bl0 + (wave * 2 + mi) * 16 + l15;
#pragma unroll
    for (int kt = 0; kt < 2; ++kt)
      aS[mi][kt] = *(const f16x8*)(Sg + (size_t)bl * 4096 + i * 64 + kt * 32 + quad * 8);
    const float* fp = F + ((size_t)(c0 + bl) * NFIELD + i) * DIM + quad * 8;
#pragma unroll
    for (int kt = 0; kt < 4; ++kt) {
      fr[mi][2 * kt]     = *(const float4*)(fp + kt * 32);
      fr[mi][2 * kt + 1] = *(const float4*)(fp + kt * 32 + 4);
    }
  }
  __syncthreads();

  f32x4 acc[2][8];
#pragma unroll
  for (int mi = 0; mi < 2; ++mi)
#pragma unroll
    for (int nt = 0; nt < 8; ++nt) acc[mi][nt] = (f32x4){0.f, 0.f, 0.f, 0.f};

#pragma unroll
  for (int kt = 0; kt < 6; ++kt) {
    f16x8 af[2];
#pragma unroll
    for (int mi = 0; mi < 2; ++mi) {
      if (kt < 2) af[mi] = aS[mi][kt];
      else        af[mi] = cvt8(fr[mi][2 * (kt - 2)], fr[mi][2 * (kt - 2) + 1]);
    }
#pragma unroll
    for (int nt = 0; nt < 8; ++nt) {
      f16x8 bf = *(const f16x8*)&sBt[(nt * 16 + l15) * 200 + kt * 32 + quad * 8];
      acc[0][nt] = __builtin_amdgcn_mfma_f32_16x16x32_f16(af[0], bf, acc[0][nt], 0, 0, 0);
      acc[1][nt] = __builtin_amdgcn_mfma_f32_16x16x32_f16(af[1], bf, acc[1][nt], 0, 0, 0);
    }
  }

#pragma unroll
  for (int mi = 0; mi < 2; ++mi) {
    const int blr = bl0 + (wave * 2 + mi) * 16 + quad * 4;
#pragma unroll
    for (int nt = 0; nt < 8; ++nt) {
      const int d = nt * 16 + l15;
#pragma unroll
      for (int r = 0; r < 4; ++r) {
        const size_t gb = (size_t)(c0 + blr + r);
        Out[(gb * NFIELD + i) * DIM + d] = acc[mi][nt][r];
      }
    }
  }
}

extern "C" void kernel_launch(void* const* d_in, const int* in_sizes, int n_in,
                              void* d_out, int out_size, void* d_ws, size_t ws_size,
                              hipStream_t stream) {
  const float* F  = (const float*)d_in[0];
  const float* W  = (const float*)d_in[1];
  const float* Kw = (const float*)d_in[2];
  const float* Qw = (const float*)d_in[3];
  float* Out = (float*)d_out;

  // workspace layout: Wt (1 MB) | Kh (32 KB) | Qh (32 KB) | S (CB*4096 fp16)
  _Float16* Wt = (_Float16*)d_ws;
  _Float16* Kh = Wt + (size_t)NFIELD * DIM * NFIELD;
  _Float16* Qh = Kh + DIM * DIM;
  _Float16* Sg = Qh + DIM * DIM;
  const size_t fixed_bytes = ((size_t)NFIELD * DIM * NFIELD + 2 * DIM * DIM) * sizeof(_Float16);
  size_t avail = (ws_size > fixed_bytes) ? (ws_size - fixed_bytes) : 0;
  int CB = BTOT;  // batches per chunk; shrink if workspace is small
  while (CB > 128 && (size_t)CB * NFIELD * NFIELD * sizeof(_Float16) > avail) CB >>= 1;

  prep_kernel<<<dim3(NFIELD + 2), 256, 0, stream>>>(W, Kw, Qw, Wt, Kh, Qh);
  for (int c0 = 0; c0 < BTOT; c0 += CB) {
    s_kernel<<<dim3(CB / NB), 256, 0, stream>>>(F, Kh, Sg, c0);
    out_kernel<<<dim3(CB / 128, NFIELD), 256, 0, stream>>>(F, Sg, Wt, Qh, Out, c0);
  }
}

// Round 2
// 556.471 us; speedup vs baseline: 1.1688x; 1.0898x over previous
//
#include <hip/hip_runtime.h>
#include <stdint.h>

typedef _Float16 f16x8 __attribute__((ext_vector_type(8)));
typedef _Float16 f16x4 __attribute__((ext_vector_type(4)));
typedef float    f32x4 __attribute__((ext_vector_type(4)));

#define NFIELD 64
#define DIM    128
#define BTOT   8192
#define NB     8   // batches per s_kernel block

__device__ __forceinline__ f16x8 cvt8(float4 a, float4 b) {
  f16x8 h;
  h[0] = (_Float16)a.x; h[1] = (_Float16)a.y; h[2] = (_Float16)a.z; h[3] = (_Float16)a.w;
  h[4] = (_Float16)b.x; h[5] = (_Float16)b.y; h[6] = (_Float16)b.z; h[7] = (_Float16)b.w;
  return h;
}

// ---------------- prep: fp16 conversions + W transpose into workspace ----------------
// Wt[i][d][j] = W[i][j][d] (fp16), Kh = fp16(K_w), Qh = fp16(Q_w)
// blocks 0..255: W transpose (4 blocks per field i, each covers 32 d's)
// block 256: Kh, block 257: Qh (float4-vectorized)
__global__ void prep_kernel(const float* __restrict__ W,
                            const float* __restrict__ Kw,
                            const float* __restrict__ Qw,
                            _Float16* __restrict__ Wt,
                            _Float16* __restrict__ Kh,
                            _Float16* __restrict__ Qh) {
  const int blk = blockIdx.x, t = threadIdx.x;
  if (blk < NFIELD * 4) {
    const int i = blk >> 2, dq = blk & 3;
    const float* Wi = W + (size_t)i * NFIELD * DIM;
    _Float16* Wo = Wt + (size_t)i * DIM * NFIELD;
    for (int idx = t; idx < 32 * NFIELD; idx += 256) {
      int d = dq * 32 + (idx >> 6), j = idx & 63;
      Wo[d * 64 + j] = (_Float16)Wi[j * DIM + d];
    }
  } else if (blk == NFIELD * 4) {
    const float4* src = (const float4*)Kw;
    for (int u = t; u < DIM * DIM / 4; u += 256) {
      float4 v = src[u];
      f16x4 h; h[0] = (_Float16)v.x; h[1] = (_Float16)v.y; h[2] = (_Float16)v.z; h[3] = (_Float16)v.w;
      *(f16x4*)&Kh[u * 4] = h;
    }
  } else {
    const float4* src = (const float4*)Qw;
    for (int u = t; u < DIM * DIM / 4; u += 256) {
      float4 v = src[u];
      f16x4 h; h[0] = (_Float16)v.x; h[1] = (_Float16)v.y; h[2] = (_Float16)v.z; h[3] = (_Float16)v.w;
      *(f16x4*)&Qh[u * 4] = h;
    }
  }
}

// ---------------- kernel A: S[b] = F_b @ (F_b @ Kw^T)^T, stored fp16 ----------------
// NB batches per block, 4 waves, 3 blocks/CU (48 KB LDS).
// Operand-swapped MFMAs so every C-fragment is row-contiguous:
//   Kf phase: mfma(Kh-rows, F-rows) -> D[m=e, n=j] -> ds_write_b64 into sKf[j][e]
//   S  phase: mfma(Kf-rows, F-rows) -> D[m=j, n=i] -> f16x4 store direct to Sg[b][i][j]
// F prefetched 2 batches ahead through registers. LDS XOR-swizzle byte^=(row&7)<<4.
__global__ __launch_bounds__(256, 3)
void s_kernel(const float* __restrict__ F,
              const _Float16* __restrict__ Kh,
              _Float16* __restrict__ Sg, int c0) {
  __shared__ __attribute__((aligned(16))) _Float16 sF[2][64 * 128];  // 2 x 16 KB, rows 256B
  __shared__ __attribute__((aligned(16))) _Float16 sKf[64 * 128];    // 16 KB, rows 256B
  const int t = threadIdx.x;
  const int lane = t & 63, wave = t >> 6;
  const int l15 = lane & 15, quad = lane >> 4;
  const int bbase = blockIdx.x * NB;

  // Kh A-fragments for this wave's two e-tiles (rows e=(2w+eh)*16+l15), loaded once
  f16x8 kh[2][4];
#pragma unroll
  for (int eh = 0; eh < 2; ++eh)
#pragma unroll
    for (int kt = 0; kt < 4; ++kt)
      kh[eh][kt] = *(const f16x8*)(Kh + ((wave * 2 + eh) * 16 + l15) * DIM + kt * 32 + quad * 8);

  float4 fr[8];
  // prologue: stage batch 0 into sF[0]
  {
    const float4* Fb4 = (const float4*)(F + (size_t)(c0 + bbase) * (NFIELD * DIM));
#pragma unroll
    for (int k = 0; k < 4; ++k) {
      int u = t + k * 256;
      fr[2 * k]     = Fb4[2 * u];
      fr[2 * k + 1] = Fb4[2 * u + 1];
    }
#pragma unroll
    for (int k = 0; k < 4; ++k) {
      int u = t + k * 256;
      int row = u >> 4, c8 = u & 15;
      *(f16x8*)((char*)&sF[0][0] + row * 256 + ((c8 * 16) ^ ((row & 7) << 4))) =
          cvt8(fr[2 * k], fr[2 * k + 1]);
    }
  }
  // issue loads for batch 1 (land during batch-0 compute)
  {
    const float4* Fb4 = (const float4*)(F + (size_t)(c0 + bbase + 1) * (NFIELD * DIM));
#pragma unroll
    for (int k = 0; k < 4; ++k) {
      int u = t + k * 256;
      fr[2 * k]     = Fb4[2 * u];
      fr[2 * k + 1] = Fb4[2 * u + 1];
    }
  }
  __syncthreads();

  for (int bi = 0; bi < NB; ++bi) {
    const int cur = bi & 1;
    const char* sFc = (const char*)&sF[cur][0];

    // ---- segment 1: KfT tiles. Wave owns e-tiles {2w, 2w+1} (m axis = e).
#pragma unroll
    for (int jt = 0; jt < 4; ++jt) {
      f16x8 bf[4];
#pragma unroll
      for (int kt = 0; kt < 4; ++kt) {
        int row = jt * 16 + l15;
        bf[kt] = *(const f16x8*)(sFc + row * 256 + ((kt * 64 + quad * 16) ^ ((row & 7) << 4)));
      }
      f32x4 a0 = {0.f, 0.f, 0.f, 0.f}, a1 = {0.f, 0.f, 0.f, 0.f};
#pragma unroll
      for (int kt = 0; kt < 4; ++kt) {
        a0 = __builtin_amdgcn_mfma_f32_16x16x32_f16(kh[0][kt], bf[kt], a0, 0, 0, 0);
        a1 = __builtin_amdgcn_mfma_f32_16x16x32_f16(kh[1][kt], bf[kt], a1, 0, 0, 0);
      }
      // D[m=e, n=j]: e = (2w+eh)*16 + quad*4 + r, j = jt*16 + l15  ->  sKf[j][e], r contiguous
      const int j = jt * 16 + l15;
      const int eb0 = (wave * 2) * 32 + quad * 8;  // byte offset of e for eh=0
      f16x4 h0, h1;
#pragma unroll
      for (int r = 0; r < 4; ++r) { h0[r] = (_Float16)a0[r]; h1[r] = (_Float16)a1[r]; }
      *(f16x4*)((char*)sKf + j * 256 + ((eb0)      ^ ((j & 7) << 4))) = h0;
      *(f16x4*)((char*)sKf + j * 256 + ((eb0 + 32) ^ ((j & 7) << 4))) = h1;
    }

    // stage batch bi+1 into sF[cur^1] (regs loaded one iteration ago)
    if (bi + 1 < NB) {
#pragma unroll
      for (int k = 0; k < 4; ++k) {
        int u = t + k * 256;
        int row = u >> 4, c8 = u & 15;
        *(f16x8*)((char*)&sF[cur ^ 1][0] + row * 256 + ((c8 * 16) ^ ((row & 7) << 4))) =
            cvt8(fr[2 * k], fr[2 * k + 1]);
      }
      // issue loads for batch bi+2 (fr now free)
      if (bi + 2 < NB) {
        const float4* Fb4 = (const float4*)(F + (size_t)(c0 + bbase + bi + 2) * (NFIELD * DIM));
#pragma unroll
        for (int k = 0; k < 4; ++k) {
          int u = t + k * 256;
          fr[2 * k]     = Fb4[2 * u];
          fr[2 * k + 1] = Fb4[2 * u + 1];
        }
      }
    }
    __syncthreads();  // sKf ready; sF[cur^1] staged

    // ---- segment 2: S tiles. Wave owns j m-tile = wave. D[m=j, n=i] -> Sg[b][i][j].
    f16x8 kfA[4];
#pragma unroll
    for (int kt = 0; kt < 4; ++kt) {
      int row = wave * 16 + l15;
      kfA[kt] = *(const f16x8*)((const char*)sKf + row * 256 +
                                ((kt * 64 + quad * 16) ^ ((row & 7) << 4)));
    }
    _Float16* dst = Sg + (size_t)(bbase + bi) * (NFIELD * NFIELD);
#pragma unroll
    for (int it = 0; it < 4; ++it) {
      f16x8 bf[4];
#pragma unroll
      for (int kt = 0; kt < 4; ++kt) {
        int row = it * 16 + l15;
        bf[kt] = *(const f16x8*)(sFc + row * 256 + ((kt * 64 + quad * 16) ^ ((row & 7) << 4)));
      }
      f32x4 acc = {0.f, 0.f, 0.f, 0.f};
#pragma unroll
      for (int kt = 0; kt < 4; ++kt)
        acc = __builtin_amdgcn_mfma_f32_16x16x32_f16(kfA[kt], bf[kt], acc, 0, 0, 0);
      f16x4 sv;
#pragma unroll
      for (int r = 0; r < 4; ++r) sv[r] = (_Float16)acc[r];
      // i = it*16+l15 (fixed per lane), j = wave*16+quad*4+r (contiguous) -> 8B store
      *(f16x4*)(dst + (it * 16 + l15) * 64 + wave * 16 + quad * 4) = sv;
    }
    __syncthreads();  // protect sKf and sF[cur] from next iteration's writes
  }
}

// ---------------- kernel B: out[b,i,:] = S[b,i,:]@W[i] + F[b,i,:]@Qw^T ----------------
// grid (b-chunks of 128, i in 0..63). Augmented GEMM: [128 x 192] @ [192 x 128].
// All A fragments preloaded into registers before the barrier -> MFMA loop has no
// global latency on its critical path.
__global__ __launch_bounds__(256, 2)
void out_kernel(const float* __restrict__ F,
                const _Float16* __restrict__ Sg,
                const _Float16* __restrict__ Wt,
                const _Float16* __restrict__ Qh,
                float* __restrict__ Out, int c0) {
  __shared__ __attribute__((aligned(16))) _Float16 sBt[128 * 200];  // row stride 400B
  const int i = blockIdx.y;
  const int t = threadIdx.x;
  const int lane = t & 63, wave = t >> 6;
  const int l15 = lane & 15, quad = lane >> 4;

  // stage B^T rows: [Wt[i][d][0:64] | Qh[d][0:128]]
  const f16x8* wp = (const f16x8*)(Wt + (size_t)i * DIM * NFIELD);
#pragma unroll
  for (int k = 0; k < 4; ++k) {
    int idx = t + k * 256;
    int d = idx >> 3, jw = idx & 7;
    *(f16x8*)&sBt[d * 200 + jw * 8] = wp[idx];
  }
  const f16x8* qp = (const f16x8*)Qh;
#pragma unroll
  for (int k = 0; k < 8; ++k) {
    int idx = t + k * 256;
    int d = idx >> 4, ew = idx & 15;
    *(f16x8*)&sBt[d * 200 + 64 + ew * 8] = qp[idx];
  }

  // preload ALL A fragments: S (fp16) + F (raw fp32, converted at use)
  const int bl0 = blockIdx.x * 128;
  f16x8 aS[2][2];
  float4 fr[2][8];
#pragma unroll
  for (int mi = 0; mi < 2; ++mi) {
    const int bl = bl0 + (wave * 2 + mi) * 16 + l15;
#pragma unroll
    for (int kt = 0; kt < 2; ++kt)
      aS[mi][kt] = *(const f16x8*)(Sg + (size_t)bl * 4096 + i * 64 + kt * 32 + quad * 8);
    const float* fp = F + ((size_t)(c0 + bl) * NFIELD + i) * DIM + quad * 8;
#pragma unroll
    for (int kt = 0; kt < 4; ++kt) {
      fr[mi][2 * kt]     = *(const float4*)(fp + kt * 32);
      fr[mi][2 * kt + 1] = *(const float4*)(fp + kt * 32 + 4);
    }
  }
  __syncthreads();

  f32x4 acc[2][8];
#pragma unroll
  for (int mi = 0; mi < 2; ++mi)
#pragma unroll
    for (int nt = 0; nt < 8; ++nt) acc[mi][nt] = (f32x4){0.f, 0.f, 0.f, 0.f};

#pragma unroll
  for (int kt = 0; kt < 6; ++kt) {
    f16x8 af[2];
#pragma unroll
    for (int mi = 0; mi < 2; ++mi) {
      if (kt < 2) af[mi] = aS[mi][kt];
      else        af[mi] = cvt8(fr[mi][2 * (kt - 2)], fr[mi][2 * (kt - 2) + 1]);
    }
#pragma unroll
    for (int nt = 0; nt < 8; ++nt) {
      f16x8 bf = *(const f16x8*)&sBt[(nt * 16 + l15) * 200 + kt * 32 + quad * 8];
      acc[0][nt] = __builtin_amdgcn_mfma_f32_16x16x32_f16(af[0], bf, acc[0][nt], 0, 0, 0);
      acc[1][nt] = __builtin_amdgcn_mfma_f32_16x16x32_f16(af[1], bf, acc[1][nt], 0, 0, 0);
    }
  }

#pragma unroll
  for (int mi = 0; mi < 2; ++mi) {
    const int blr = bl0 + (wave * 2 + mi) * 16 + quad * 4;
#pragma unroll
    for (int nt = 0; nt < 8; ++nt) {
      const int d = nt * 16 + l15;
#pragma unroll
      for (int r = 0; r < 4; ++r) {
        const size_t gb = (size_t)(c0 + blr + r);
        Out[(gb * NFIELD + i) * DIM + d] = acc[mi][nt][r];
      }
    }
  }
}

extern "C" void kernel_launch(void* const* d_in, const int* in_sizes, int n_in,
                              void* d_out, int out_size, void* d_ws, size_t ws_size,
                              hipStream_t stream) {
  const float* F  = (const float*)d_in[0];
  const float* W  = (const float*)d_in[1];
  const float* Kw = (const float*)d_in[2];
  const float* Qw = (const float*)d_in[3];
  float* Out = (float*)d_out;

  // workspace layout: Wt (1 MB) | Kh (32 KB) | Qh (32 KB) | S (CB*4096 fp16)
  _Float16* Wt = (_Float16*)d_ws;
  _Float16* Kh = Wt + (size_t)NFIELD * DIM * NFIELD;
  _Float16* Qh = Kh + DIM * DIM;
  _Float16* Sg = Qh + DIM * DIM;
  const size_t fixed_bytes = ((size_t)NFIELD * DIM * NFIELD + 2 * DIM * DIM) * sizeof(_Float16);
  size_t avail = (ws_size > fixed_bytes) ? (ws_size - fixed_bytes) : 0;
  int CB = BTOT;  // batches per chunk; shrink if workspace is small
  while (CB > 128 && (size_t)CB * NFIELD * NFIELD * sizeof(_Float16) > avail) CB >>= 1;

  prep_kernel<<<dim3(NFIELD * 4 + 2), 256, 0, stream>>>(W, Kw, Qw, Wt, Kh, Qh);
  for (int c0 = 0; c0 < BTOT; c0 += CB) {
    s_kernel<<<dim3(CB / NB), 256, 0, stream>>>(F, Kh, Sg, c0);
    out_kernel<<<dim3(CB / 128, NFIELD), 256, 0, stream>>>(F, Sg, Wt, Qh, Out, c0);
  }
}